// Round 10
// baseline (161.241 us; speedup 1.0000x reference)
//
#include <hip/hip_runtime.h>
#include <hip/hip_bf16.h>
#include <stdint.h>

#define BB 2
#define CC 256
#define HH 96
#define WW 320
#define NPIX 16384
#define NLAY 5
#define KDIM 1280   // CC*NLAY
#define NDIM 32768  // BB*NPIX
#define NKT (KDIM / 32)   // 40 K-tiles
#define NGRP 256    // NDIM/128 output row groups (k6 N-tiles)

typedef float f32x4 __attribute__((ext_vector_type(4)));
typedef float f32x2 __attribute__((ext_vector_type(2)));
typedef __bf16 bf16x8 __attribute__((ext_vector_type(8)));
typedef __bf16 bf16x4 __attribute__((ext_vector_type(4)));

// ---------- R10: integ layout permuted (B,H,W,C) -> (B,W,H,C) ----------
// k2 (the H-scan) was at 3.2 TB/s = half the copy ceiling: its h-walk strode
// 320KB/step, touching 96 scattered lines per block over a 30MB span (DRAM
// page churn chip-wide). New layout: h-stride = 1KB, so each k2 block owns
// ONE contiguous 96KB slab. k1f stores stay 128B full-line single-owner
// segments (96KB stride now); k4 taps swap xi/yi stride roles (L2-resident
// either way). Math/order bit-identical.

// ---------- K1 (+K3+K5 fused as extra blocks) ----------
__global__ __launch_bounds__(1024) void k1f(const float* __restrict__ feat,
                                            float* __restrict__ integ,
                                            const float* __restrict__ gridp,
                                            const float* __restrict__ calib,
                                            const float* __restrict__ Wc,
                                            float4* __restrict__ coords,
                                            float* __restrict__ scales,
                                            __bf16* __restrict__ Wbf,
                                            uint8_t* __restrict__ mask8) {
  const int bid = blockIdx.x;
  if (bid < 480) {
    // ---- K3/K5 part ----
    const int vbid = bid * 4 + (threadIdx.x >> 8);
    const int vt = threadIdx.x & 255;
    if (vbid >= 640) {                  // K5: repack Wc (co, c*5+n) -> bf16 (co, n*256+c)
      int o = (vbid - 640) * 256 + vt;
      int co = o / KDIM;
      int kk = o % KDIM;
      int n = kk >> 8;
      int c = kk & 255;
      Wbf[o] = (__bf16)Wc[co * KDIM + c * NLAY + n];
      return;
    }
    // K3: one thread per box.
    int box = vbid * 256 + vt;          // ((b*5+n)<<14) | pix
    int pix = box & (NPIX - 1);
    int bn = box >> 14;
    int n = bn % NLAY;
    int b = bn / NLAY;
    const float* cb = calib + b * 12;
    float c00 = cb[0], c01 = cb[1], c02 = cb[2], c03 = cb[3];
    float c10 = cb[4], c11 = cb[5], c12 = cb[6], c13 = cb[7];
    float c20 = cb[8], c21 = cb[9], c22 = cb[10], c23 = cb[11];
    float gx = gridp[pix * 3 + 0], gy = gridp[pix * 3 + 1], gz = gridp[pix * 3 + 2];
    float zoff = 32.0f * (float)n;
    const float ox[8] = {-12.5f, 12.5f, 12.5f, -12.5f, -12.5f, 12.5f, 12.5f, -12.5f};
    const float oy[8] = {-12.5f, -12.5f, 12.5f, 12.5f, -12.5f, -12.5f, 12.5f, 12.5f};
    float xmn = 1e30f, ymn = 1e30f, xmx = -1e30f, ymx = -1e30f;
#pragma unroll
    for (int k = 0; k < 8; ++k) {
      float X = gx + ox[k];
      float Y = gy + oy[k];
      float Z = gz + zoff + ((k >= 4) ? 32.0f : 0.0f);
      float px = c00 * X + c01 * Y + c02 * Z + c03;
      float py = c10 * X + c11 * Y + c12 * Z + c13;
      float pz = c20 * X + c21 * Y + c22 * Z + c23;
      float d = fmaxf(pz, 1e-6f);
      float nx = fminf(fmaxf(2.0f * (px / d) / 320.0f - 1.0f, -1.0f), 0.95f);
      float ny = fminf(fmaxf(2.0f * (py / d) / 96.0f - 1.0f, -1.0f), 0.95f);
      xmn = fminf(xmn, nx); xmx = fmaxf(xmx, nx);
      ymn = fminf(ymn, ny); ymx = fmaxf(ymx, ny);
    }
    float dx = xmx - xmn, dy = ymx - ymn;
    float area = (dx * dy) * 30720.0f + 1e-6f;
    bool vis = (area > 1e-6f) && (area < 9216.0f);
    {
      __shared__ uint32_t kf[16];
      unsigned long long bal = __ballot(vis);
      if ((threadIdx.x & 63) == 0) kf[threadIdx.x >> 6] = (bal != 0ull) ? 1u : 0u;
      __syncthreads();
      if (vt == 0) {
        int vb = threadIdx.x >> 8;      // vbid-local 0..3
        int vbid2 = bid * 4 + vb;
        int bn2 = vbid2 >> 6;
        int n2 = bn2 % NLAY, b2 = bn2 / NLAY;
        int g0 = b2 * 128 + (vbid2 & 63) * 2;
        mask8[g0 * 5 + n2]       = (uint8_t)(kf[vb * 4 + 0] | kf[vb * 4 + 1]);
        mask8[(g0 + 1) * 5 + n2] = (uint8_t)(kf[vb * 4 + 2] | kf[vb * 4 + 3]);
      }
    }
    float X0 = ((xmn + 1.0f) * 320.0f - 1.0f) * 0.5f;
    float Y0 = ((ymn + 1.0f) * 96.0f - 1.0f) * 0.5f;
    float X1 = ((xmx + 1.0f) * 320.0f - 1.0f) * 0.5f;
    float Y1 = ((ymx + 1.0f) * 96.0f - 1.0f) * 0.5f;
    coords[box] = make_float4(X0, Y0, X1, Y1);
    scales[box] = vis ? 1.0f / area : 0.0f;
    return;
  }
  // ---- K1 part: 32 channels per block, wave scans 2 channel rows ----
  __shared__ float tile[WW * 33];       // pitch 33: run-write stride 165%32=5
                                        // (2-way, free); f4-read (w+4cq) 2-way
  const int t = threadIdx.x;
  const int wave = t >> 6;
  const int lane = t & 63;
  const int kb = bid - 480;
  const int cg = kb & 7;
  const int h = (kb >> 3) % HH;
  const int b = kb / (8 * HH);
  const int c0 = cg * 32 + wave * 2;
  const float* s0 = feat + (size_t)((b * CC + c0) * HH + h) * WW;
  const float* s1 = s0 + (size_t)HH * WW;

  float va[5], vb[5];
#pragma unroll
  for (int j = 0; j < 5; ++j) va[j] = s0[lane * 5 + j];
#pragma unroll
  for (int j = 0; j < 5; ++j) vb[j] = s1[lane * 5 + j];
#pragma unroll
  for (int j = 1; j < 5; ++j) { va[j] += va[j - 1]; vb[j] += vb[j - 1]; }
  float ta = va[4], tb = vb[4];
  float ia = ta, ib = tb;
#pragma unroll
  for (int d = 1; d < 64; d <<= 1) {
    float ua = __shfl_up(ia, d, 64);
    float ub = __shfl_up(ib, d, 64);
    if (lane >= d) { ia += ua; ib += ub; }
  }
  float pa = ia - ta, pb = ib - tb;     // exclusive prefixes
#pragma unroll
  for (int j = 0; j < 5; ++j) { va[j] += pa; vb[j] += pb; }
  const int ca = wave * 2, cbn = wave * 2 + 1;
#pragma unroll
  for (int j = 0; j < 5; ++j) {
    int w = lane * 5 + j;
    tile[w * 33 + ca]  = va[j];
    tile[w * 33 + cbn] = vb[j];
  }
  __syncthreads();
  // store: (B,W,H,C) layout — addr = ((b*WW + w)*HH + h)*CC + cg*32 + cq.
  // per wave-instr: 8 x 128B full-line single-owner segments at 96KB stride.
  float* dst = integ + ((size_t)(b * WW) * HH + h) * CC + cg * 32;
  const size_t wstride = (size_t)HH * CC;
#pragma unroll
  for (int r = 0; r < 3; ++r) {
    int idx = r * 1024 + t;             // 0..2559
    if (idx < 2560) {
      int w = idx >> 3;
      int cq = (idx & 7) * 4;
      float4 o = make_float4(tile[w * 33 + cq + 0], tile[w * 33 + cq + 1],
                             tile[w * 33 + cq + 2], tile[w * 33 + cq + 3]);
      *(float4*)(dst + (size_t)w * wstride + cq) = o;
    }
  }
}

// ---------- K2: cumsum along H, in place on (B,W,H,C) ----------
// R10: block (b,w) owns ONE contiguous 96KB slab; h-stride = CC*4 = 1KB.
// Two-level scan, f32x4 per lane, 24-deep independent-load ILP. Grid 640.
__global__ __launch_bounds__(256) void k2_scan(float* __restrict__ integ) {
  const int blk = blockIdx.x;            // (b, w)
  const int w = blk % WW;
  const int b = blk / WW;
  const int g = threadIdx.x >> 6;        // 0..3 h-group
  const int l = threadIdx.x & 63;
  float* base = integ + ((size_t)(b * WW + w) * HH + g * 24) * CC + l * 4;
  const size_t stride = (size_t)CC;      // 1KB h-stride, contiguous slab
  f32x4 v[24];
#pragma unroll
  for (int i = 0; i < 24; ++i) v[i] = *(const f32x4*)(base + (size_t)i * stride);
#pragma unroll
  for (int i = 1; i < 24; ++i) v[i] += v[i - 1];
  __shared__ f32x4 part[4][64];
  part[g][l] = v[23];
  __syncthreads();
  f32x4 off = {0.f, 0.f, 0.f, 0.f};
#pragma unroll
  for (int gg = 0; gg < 3; ++gg)
    if (gg < g) off += part[gg][l];
#pragma unroll
  for (int i = 0; i < 24; ++i) *(f32x4*)(base + (size_t)i * stride) = v[i] + off;
}

// ---------- K4: box-filtered features -> vox (bf16), K permuted to n*256+c ----------
// FOUR boxes per wave, 4-deep memory ILP, mask early-out (R5).
// R10: tap addr = ((b*WW + xi)*HH + yi)*CC + c — xi/yi stride roles swapped.
__global__ __launch_bounds__(256) void k4_vox(const float* __restrict__ integ,
                                              const float4* __restrict__ coords,
                                              const float* __restrict__ scales,
                                              __bf16* __restrict__ voxA,
                                              const uint8_t* __restrict__ mask8) {
  const int wave = threadIdx.x >> 6;
  const int lane = threadIdx.x & 63;
  const int box0 = (blockIdx.x * 4 + wave) * 4;
  {
    const int pix0 = box0 & (NPIX - 1);
    const int bn0 = box0 >> 14;
    const int n0 = bn0 % NLAY, b0 = bn0 / NLAY;
    if (mask8[((b0 * NPIX + pix0) >> 7) * 5 + n0] == 0) return;  // wave-uniform
  }
#pragma unroll
  for (int u = 0; u < 4; ++u) {
    const int box = box0 + u;
    const int pix = box & (NPIX - 1);
    const int bn = box >> 14;
    const int n = bn % NLAY;
    const int b = bn / NLAY;
    const size_t row = (size_t)(b * NPIX + pix);
    bf16x4* dst = (bf16x4*)(voxA + row * KDIM + n * CC + lane * 4);
    const float scale = scales[box];
    if (scale == 0.f) {                 // wave-uniform branch
      *dst = bf16x4{(__bf16)0.f, (__bf16)0.f, (__bf16)0.f, (__bf16)0.f};
      continue;
    }
    const float4 q = coords[box];

    float xw[4]; int xi[4];
    float yw[4]; int yi[4];
    {
      float f0 = floorf(q.x); int i0 = (int)f0; float w1 = q.x - f0;
      xw[0] = (i0 >= 0 && i0 < WW) ? (1.f - w1) : 0.f;
      xw[1] = (i0 + 1 < WW) ? w1 : 0.f;
      xi[0] = min(max(i0, 0), WW - 1); xi[1] = min(max(i0 + 1, 0), WW - 1);
      float f1 = floorf(q.z); int i1 = (int)f1; float v1 = q.z - f1;
      xw[2] = (i1 >= 0 && i1 < WW) ? -(1.f - v1) : 0.f;
      xw[3] = (i1 + 1 < WW) ? -v1 : 0.f;
      xi[2] = min(max(i1, 0), WW - 1); xi[3] = min(max(i1 + 1, 0), WW - 1);
    }
    {
      float f0 = floorf(q.y); int j0 = (int)f0; float w1 = q.y - f0;
      yw[0] = (j0 >= 0 && j0 < HH) ? (1.f - w1) : 0.f;
      yw[1] = (j0 + 1 < HH) ? w1 : 0.f;
      yi[0] = min(max(j0, 0), HH - 1); yi[1] = min(max(j0 + 1, 0), HH - 1);
      float f1 = floorf(q.w); int j1 = (int)f1; float v1 = q.w - f1;
      yw[2] = (j1 >= 0 && j1 < HH) ? -(1.f - v1) : 0.f;
      yw[3] = (j1 + 1 < HH) ? -v1 : 0.f;
      yi[2] = min(max(j1, 0), HH - 1); yi[3] = min(max(j1 + 1, 0), HH - 1);
    }
    const float* base = integ + (size_t)(b * WW) * HH * CC + lane * 4;
    f32x4 val = {0.f, 0.f, 0.f, 0.f};
#pragma unroll
    for (int jj = 0; jj < 4; ++jj) {
      if (yw[jj] == 0.f) continue;          // wave-uniform branch
      const float* rp = base + (size_t)yi[jj] * CC;
      f32x4 rs = {0.f, 0.f, 0.f, 0.f};
#pragma unroll
      for (int ii = 0; ii < 4; ++ii) {
        if (xw[ii] != 0.f) {
          f32x4 v = *(const f32x4*)(rp + (size_t)xi[ii] * HH * CC);
          rs += xw[ii] * v;
        }
      }
      val += yw[jj] * rs;
    }
    val *= scale;
    *dst = bf16x4{(__bf16)val.x, (__bf16)val.y, (__bf16)val.z, (__bf16)val.w};
  }
}

// ---------- async 16B global -> LDS ----------
__device__ __forceinline__ void glds16(const void* g, void* l) {
  __builtin_amdgcn_global_load_lds(
      (const __attribute__((address_space(1))) void*)g,
      (__attribute__((address_space(3))) void*)(uint32_t)(uintptr_t)l,
      16, 0, 0);
}

// ---------- K6: GEMM  C[co, r] = sum_k Wbf[co,k] * vox[r,k]; +bias, relu ----------
// M=256, N=32768, K=1280. 128x128 tiles, bf16 MFMA 16x16x32, 4-buffer LDS
// ring, depth-3 glds prefetch, in-flight-aware vmcnt + raw s_barrier.
// K-loop over the COMPRESSED active K-tile list (8 per visible layer). [R5]
__global__ __launch_bounds__(256) void k6_gemm(const __bf16* __restrict__ A,   // 256 x 1280
                                               const __bf16* __restrict__ Bm,  // 32768 x 1280
                                               const float* __restrict__ bias,
                                               float* __restrict__ out,
                                               const uint8_t* __restrict__ mask8) {
  __shared__ __align__(16) __bf16 As[4][128 * 32];
  __shared__ __align__(16) __bf16 Bs[4][128 * 32];
  __shared__ uint8_t ktsS[NKT];
  __shared__ int LsS;
  const int tileM = blockIdx.y * 128;
  const int tileN = blockIdx.x * 128;
  const int tid = threadIdx.x;
  const int lane = tid & 63;
  const int wave = tid >> 6;
  const int wm = (wave >> 1) * 64;
  const int wn = (wave & 1) * 64;

  if (tid == 0) {
    const uint8_t* mg = mask8 + blockIdx.x * 5;   // N-tile group == blockIdx.x
    int L = 0;
#pragma unroll
    for (int n = 0; n < NLAY; ++n)
      if (mg[n]) {
#pragma unroll
        for (int kk = 0; kk < 8; ++kk) ktsS[L++] = (uint8_t)(n * 8 + kk);
      }
    LsS = L;
  }

  f32x4 acc[4][4];
#pragma unroll
  for (int i = 0; i < 4; ++i)
#pragma unroll
    for (int j = 0; j < 4; ++j)
      acc[i][j] = f32x4{0.f, 0.f, 0.f, 0.f};

  const int r16 = lane & 15;
  const int q4 = lane >> 4;        // 0..3 -> k-chunk
  const int srow = (lane >> 2);
  const int sch = lane & 3;

  auto stage = [&](int buf, int kt) {
    const int k0 = kt * 32;
#pragma unroll
    for (int rr = 0; rr < 2; ++rr) {
      const int base_row = wave * 16 + rr * 64;
      const int row = base_row + srow;
      const int gch = sch ^ ((row >> 1) & 3);
      glds16(A  + (size_t)(tileM + row) * KDIM + k0 + gch * 8,
             (void*)(&As[buf][base_row * 32] + lane * 8));
      glds16(Bm + (size_t)(tileN + row) * KDIM + k0 + gch * 8,
             (void*)(&Bs[buf][base_row * 32] + lane * 8));
    }
  };

  __syncthreads();                       // ktsS/LsS visible
  const int L = LsS;
#pragma unroll
  for (int s = 0; s < 3; ++s)
    if (s < L) stage(s, ktsS[s]);
  for (int i = 0; i < L; ++i) {
    const int cur = i & 3;
    const int rem = L - i;               // stages in flight = min(rem, 3)
    if (rem >= 3)      __builtin_amdgcn_s_waitcnt(0xF78);  // vmcnt(8)
    else if (rem == 2) __builtin_amdgcn_s_waitcnt(0xF74);  // vmcnt(4)
    else               __builtin_amdgcn_s_waitcnt(0xF70);  // vmcnt(0)
    __builtin_amdgcn_s_barrier();
    if (i + 3 < L) stage((i + 3) & 3, ktsS[i + 3]);   // async prefetch, depth 3
    bf16x8 af[4], bg[4];
#pragma unroll
    for (int ii = 0; ii < 4; ++ii) {
      int m = wm + ii * 16 + r16;
      af[ii] = *(const bf16x8*)(&As[cur][m * 32] + (q4 ^ ((m >> 1) & 3)) * 8);
    }
#pragma unroll
    for (int j = 0; j < 4; ++j) {
      int nr = wn + j * 16 + r16;
      bg[j] = *(const bf16x8*)(&Bs[cur][nr * 32] + (q4 ^ ((nr >> 1) & 3)) * 8);
    }
#pragma unroll
    for (int ii = 0; ii < 4; ++ii)
#pragma unroll
      for (int j = 0; j < 4; ++j)
        acc[ii][j] = __builtin_amdgcn_mfma_f32_16x16x32_bf16(af[ii], bg[j], acc[ii][j], 0, 0, 0);
  }

#pragma unroll
  for (int i = 0; i < 4; ++i) {
#pragma unroll
    for (int j = 0; j < 4; ++j) {
      int nn = tileN + wn + j * 16 + r16;
      int bI = nn >> 14;
      int pix = nn & (NPIX - 1);
#pragma unroll
      for (int r = 0; r < 4; ++r) {
        int co = tileM + wm + i * 16 + q4 * 4 + r;
        float v = acc[i][j][r] + bias[co];
        out[(size_t)(bI * CC + co) * NPIX + pix] = fmaxf(v, 0.f);
      }
    }
  }
}

extern "C" void kernel_launch(void* const* d_in, const int* in_sizes, int n_in,
                              void* d_out, int out_size, void* d_ws, size_t ws_size,
                              hipStream_t stream) {
  const float* feat  = (const float*)d_in[0];
  const float* calib = (const float*)d_in[1];
  const float* grid  = (const float*)d_in[2];
  const float* Wc    = (const float*)d_in[3];
  const float* bc    = (const float*)d_in[4];
  float* out = (float*)d_out;

  char* ws = (char*)d_ws;
  const size_t SZ_INTEG = (size_t)BB * HH * WW * CC * 4;   // 62,914,560
  const size_t SZ_VOX   = (size_t)NDIM * KDIM * 2;         // 83,886,080
  const size_t SZ_WBF   = (size_t)CC * KDIM * 2;           //    655,360
  const size_t SZ_CRD   = (size_t)BB * NLAY * NPIX * 16;   //  2,621,440
  const size_t SZ_SCL   = (size_t)BB * NLAY * NPIX * 4;    //    655,360
  const size_t SZ_MSK   = (size_t)NGRP * NLAY;             //      1,280
  if (ws_size < SZ_INTEG + SZ_VOX + SZ_WBF + SZ_CRD + SZ_SCL + SZ_MSK) return;

  float*   integ  = (float*)ws;
  __bf16*  voxA   = (__bf16*)(ws + SZ_INTEG);
  __bf16*  Wbf    = (__bf16*)(ws + SZ_INTEG + SZ_VOX);
  float4*  coords = (float4*)(ws + SZ_INTEG + SZ_VOX + SZ_WBF);
  float*   scales = (float*)(ws + SZ_INTEG + SZ_VOX + SZ_WBF + SZ_CRD);
  uint8_t* mask8  = (uint8_t*)(ws + SZ_INTEG + SZ_VOX + SZ_WBF + SZ_CRD + SZ_SCL);

  k1f<<<dim3(BB * HH * 8 + 480), dim3(1024), 0, stream>>>(
      feat, integ, grid, calib, Wc, coords, scales, Wbf, mask8);
  k2_scan<<<dim3(BB * WW), dim3(256), 0, stream>>>(integ);
  k4_vox<<<dim3(BB * NLAY * NPIX / 16), dim3(256), 0, stream>>>(integ, coords, scales, voxA, mask8);
  k6_gemm<<<dim3(NDIM / 128, 2), dim3(256), 0, stream>>>(Wbf, voxA, bc, out, mask8);
}

// Round 11
// 159.227 us; speedup vs baseline: 1.0126x; 1.0126x over previous
//
#include <hip/hip_runtime.h>
#include <hip/hip_bf16.h>
#include <stdint.h>

#define BB 2
#define CC 256
#define HH 96
#define WW 320
#define NPIX 16384
#define NLAY 5
#define KDIM 1280   // CC*NLAY
#define NDIM 32768  // BB*NPIX
#define NKT (KDIM / 32)   // 40 K-tiles
#define NGRP 256    // NDIM/128 output row groups (k6 N-tiles)

typedef float f32x4 __attribute__((ext_vector_type(4)));
typedef float f32x2 __attribute__((ext_vector_type(2)));
typedef __bf16 bf16x8 __attribute__((ext_vector_type(8)));
typedef __bf16 bf16x4 __attribute__((ext_vector_type(4)));

// ---------- R11: out-of-place k2 via buffer rotation ----------
// R10 (fully contiguous k2 slabs) was NULL -> k2's deficit is not address
// locality. Last structural difference vs the 6.6TB/s fill / 6.3TB/s copy:
// k2 was IN-PLACE RMW (write lands exactly where it just read -> DRAM
// read/write turnaround per line). Rotation: k1f -> X (vox region, dead
// until k4), k2 reads X writes Y (integ slot) = pure stream copy+scan,
// k4 reads Y and overwrites X with voxA (safe: stream-ordered).
// integ layout (B,W,H,C) kept from R10 (neutral, contiguous slabs).

// ---------- K1 (+K3+K5 fused as extra blocks) ----------
__global__ __launch_bounds__(1024) void k1f(const float* __restrict__ feat,
                                            float* __restrict__ integ,
                                            const float* __restrict__ gridp,
                                            const float* __restrict__ calib,
                                            const float* __restrict__ Wc,
                                            float4* __restrict__ coords,
                                            float* __restrict__ scales,
                                            __bf16* __restrict__ Wbf,
                                            uint8_t* __restrict__ mask8) {
  const int bid = blockIdx.x;
  if (bid < 480) {
    // ---- K3/K5 part ----
    const int vbid = bid * 4 + (threadIdx.x >> 8);
    const int vt = threadIdx.x & 255;
    if (vbid >= 640) {                  // K5: repack Wc (co, c*5+n) -> bf16 (co, n*256+c)
      int o = (vbid - 640) * 256 + vt;
      int co = o / KDIM;
      int kk = o % KDIM;
      int n = kk >> 8;
      int c = kk & 255;
      Wbf[o] = (__bf16)Wc[co * KDIM + c * NLAY + n];
      return;
    }
    // K3: one thread per box.
    int box = vbid * 256 + vt;          // ((b*5+n)<<14) | pix
    int pix = box & (NPIX - 1);
    int bn = box >> 14;
    int n = bn % NLAY;
    int b = bn / NLAY;
    const float* cb = calib + b * 12;
    float c00 = cb[0], c01 = cb[1], c02 = cb[2], c03 = cb[3];
    float c10 = cb[4], c11 = cb[5], c12 = cb[6], c13 = cb[7];
    float c20 = cb[8], c21 = cb[9], c22 = cb[10], c23 = cb[11];
    float gx = gridp[pix * 3 + 0], gy = gridp[pix * 3 + 1], gz = gridp[pix * 3 + 2];
    float zoff = 32.0f * (float)n;
    const float ox[8] = {-12.5f, 12.5f, 12.5f, -12.5f, -12.5f, 12.5f, 12.5f, -12.5f};
    const float oy[8] = {-12.5f, -12.5f, 12.5f, 12.5f, -12.5f, -12.5f, 12.5f, 12.5f};
    float xmn = 1e30f, ymn = 1e30f, xmx = -1e30f, ymx = -1e30f;
#pragma unroll
    for (int k = 0; k < 8; ++k) {
      float X = gx + ox[k];
      float Y = gy + oy[k];
      float Z = gz + zoff + ((k >= 4) ? 32.0f : 0.0f);
      float px = c00 * X + c01 * Y + c02 * Z + c03;
      float py = c10 * X + c11 * Y + c12 * Z + c13;
      float pz = c20 * X + c21 * Y + c22 * Z + c23;
      float d = fmaxf(pz, 1e-6f);
      float nx = fminf(fmaxf(2.0f * (px / d) / 320.0f - 1.0f, -1.0f), 0.95f);
      float ny = fminf(fmaxf(2.0f * (py / d) / 96.0f - 1.0f, -1.0f), 0.95f);
      xmn = fminf(xmn, nx); xmx = fmaxf(xmx, nx);
      ymn = fminf(ymn, ny); ymx = fmaxf(ymx, ny);
    }
    float dx = xmx - xmn, dy = ymx - ymn;
    float area = (dx * dy) * 30720.0f + 1e-6f;
    bool vis = (area > 1e-6f) && (area < 9216.0f);
    {
      __shared__ uint32_t kf[16];
      unsigned long long bal = __ballot(vis);
      if ((threadIdx.x & 63) == 0) kf[threadIdx.x >> 6] = (bal != 0ull) ? 1u : 0u;
      __syncthreads();
      if (vt == 0) {
        int vb = threadIdx.x >> 8;      // vbid-local 0..3
        int vbid2 = bid * 4 + vb;
        int bn2 = vbid2 >> 6;
        int n2 = bn2 % NLAY, b2 = bn2 / NLAY;
        int g0 = b2 * 128 + (vbid2 & 63) * 2;
        mask8[g0 * 5 + n2]       = (uint8_t)(kf[vb * 4 + 0] | kf[vb * 4 + 1]);
        mask8[(g0 + 1) * 5 + n2] = (uint8_t)(kf[vb * 4 + 2] | kf[vb * 4 + 3]);
      }
    }
    float X0 = ((xmn + 1.0f) * 320.0f - 1.0f) * 0.5f;
    float Y0 = ((ymn + 1.0f) * 96.0f - 1.0f) * 0.5f;
    float X1 = ((xmx + 1.0f) * 320.0f - 1.0f) * 0.5f;
    float Y1 = ((ymx + 1.0f) * 96.0f - 1.0f) * 0.5f;
    coords[box] = make_float4(X0, Y0, X1, Y1);
    scales[box] = vis ? 1.0f / area : 0.0f;
    return;
  }
  // ---- K1 part: 32 channels per block, wave scans 2 channel rows ----
  __shared__ float tile[WW * 33];       // pitch 33: run-write stride 165%32=5
                                        // (2-way, free); f4-read (w+4cq) 2-way
  const int t = threadIdx.x;
  const int wave = t >> 6;
  const int lane = t & 63;
  const int kb = bid - 480;
  const int cg = kb & 7;
  const int h = (kb >> 3) % HH;
  const int b = kb / (8 * HH);
  const int c0 = cg * 32 + wave * 2;
  const float* s0 = feat + (size_t)((b * CC + c0) * HH + h) * WW;
  const float* s1 = s0 + (size_t)HH * WW;

  float va[5], vb[5];
#pragma unroll
  for (int j = 0; j < 5; ++j) va[j] = s0[lane * 5 + j];
#pragma unroll
  for (int j = 0; j < 5; ++j) vb[j] = s1[lane * 5 + j];
#pragma unroll
  for (int j = 1; j < 5; ++j) { va[j] += va[j - 1]; vb[j] += vb[j - 1]; }
  float ta = va[4], tb = vb[4];
  float ia = ta, ib = tb;
#pragma unroll
  for (int d = 1; d < 64; d <<= 1) {
    float ua = __shfl_up(ia, d, 64);
    float ub = __shfl_up(ib, d, 64);
    if (lane >= d) { ia += ua; ib += ub; }
  }
  float pa = ia - ta, pb = ib - tb;     // exclusive prefixes
#pragma unroll
  for (int j = 0; j < 5; ++j) { va[j] += pa; vb[j] += pb; }
  const int ca = wave * 2, cbn = wave * 2 + 1;
#pragma unroll
  for (int j = 0; j < 5; ++j) {
    int w = lane * 5 + j;
    tile[w * 33 + ca]  = va[j];
    tile[w * 33 + cbn] = vb[j];
  }
  __syncthreads();
  // store: (B,W,H,C) layout — addr = ((b*WW + w)*HH + h)*CC + cg*32 + cq.
  // per wave-instr: 8 x 128B full-line single-owner segments at 96KB stride.
  float* dst = integ + ((size_t)(b * WW) * HH + h) * CC + cg * 32;
  const size_t wstride = (size_t)HH * CC;
#pragma unroll
  for (int r = 0; r < 3; ++r) {
    int idx = r * 1024 + t;             // 0..2559
    if (idx < 2560) {
      int w = idx >> 3;
      int cq = (idx & 7) * 4;
      float4 o = make_float4(tile[w * 33 + cq + 0], tile[w * 33 + cq + 1],
                             tile[w * 33 + cq + 2], tile[w * 33 + cq + 3]);
      *(float4*)(dst + (size_t)w * wstride + cq) = o;
    }
  }
}

// ---------- K2: cumsum along H, OUT-OF-PLACE on (B,W,H,C) ----------
// R11: reads src (X), writes dst (Y) — read region != write region, so the
// DRAM bus streams like the 6.3TB/s copy instead of per-line read/write
// turnaround. Block (b,w) owns one contiguous 96KB slab in each buffer.
__global__ __launch_bounds__(256) void k2_scan(const float* __restrict__ src,
                                               float* __restrict__ dst) {
  const int blk = blockIdx.x;            // (b, w)
  const int w = blk % WW;
  const int b = blk / WW;
  const int g = threadIdx.x >> 6;        // 0..3 h-group
  const int l = threadIdx.x & 63;
  const size_t off = ((size_t)(b * WW + w) * HH + g * 24) * CC + l * 4;
  const float* s = src + off;
  float* d = dst + off;
  const size_t stride = (size_t)CC;      // 1KB h-stride, contiguous slab
  f32x4 v[24];
#pragma unroll
  for (int i = 0; i < 24; ++i) v[i] = *(const f32x4*)(s + (size_t)i * stride);
#pragma unroll
  for (int i = 1; i < 24; ++i) v[i] += v[i - 1];
  __shared__ f32x4 part[4][64];
  part[g][l] = v[23];
  __syncthreads();
  f32x4 off4 = {0.f, 0.f, 0.f, 0.f};
#pragma unroll
  for (int gg = 0; gg < 3; ++gg)
    if (gg < g) off4 += part[gg][l];
#pragma unroll
  for (int i = 0; i < 24; ++i) *(f32x4*)(d + (size_t)i * stride) = v[i] + off4;
}

// ---------- K4: box-filtered features -> vox (bf16), K permuted to n*256+c ----------
// FOUR boxes per wave, 4-deep memory ILP, mask early-out (R5).
// (B,W,H,C) taps: addr = ((b*WW + xi)*HH + yi)*CC + c.
__global__ __launch_bounds__(256) void k4_vox(const float* __restrict__ integ,
                                              const float4* __restrict__ coords,
                                              const float* __restrict__ scales,
                                              __bf16* __restrict__ voxA,
                                              const uint8_t* __restrict__ mask8) {
  const int wave = threadIdx.x >> 6;
  const int lane = threadIdx.x & 63;
  const int box0 = (blockIdx.x * 4 + wave) * 4;
  {
    const int pix0 = box0 & (NPIX - 1);
    const int bn0 = box0 >> 14;
    const int n0 = bn0 % NLAY, b0 = bn0 / NLAY;
    if (mask8[((b0 * NPIX + pix0) >> 7) * 5 + n0] == 0) return;  // wave-uniform
  }
#pragma unroll
  for (int u = 0; u < 4; ++u) {
    const int box = box0 + u;
    const int pix = box & (NPIX - 1);
    const int bn = box >> 14;
    const int n = bn % NLAY;
    const int b = bn / NLAY;
    const size_t row = (size_t)(b * NPIX + pix);
    bf16x4* dst = (bf16x4*)(voxA + row * KDIM + n * CC + lane * 4);
    const float scale = scales[box];
    if (scale == 0.f) {                 // wave-uniform branch
      *dst = bf16x4{(__bf16)0.f, (__bf16)0.f, (__bf16)0.f, (__bf16)0.f};
      continue;
    }
    const float4 q = coords[box];

    float xw[4]; int xi[4];
    float yw[4]; int yi[4];
    {
      float f0 = floorf(q.x); int i0 = (int)f0; float w1 = q.x - f0;
      xw[0] = (i0 >= 0 && i0 < WW) ? (1.f - w1) : 0.f;
      xw[1] = (i0 + 1 < WW) ? w1 : 0.f;
      xi[0] = min(max(i0, 0), WW - 1); xi[1] = min(max(i0 + 1, 0), WW - 1);
      float f1 = floorf(q.z); int i1 = (int)f1; float v1 = q.z - f1;
      xw[2] = (i1 >= 0 && i1 < WW) ? -(1.f - v1) : 0.f;
      xw[3] = (i1 + 1 < WW) ? -v1 : 0.f;
      xi[2] = min(max(i1, 0), WW - 1); xi[3] = min(max(i1 + 1, 0), WW - 1);
    }
    {
      float f0 = floorf(q.y); int j0 = (int)f0; float w1 = q.y - f0;
      yw[0] = (j0 >= 0 && j0 < HH) ? (1.f - w1) : 0.f;
      yw[1] = (j0 + 1 < HH) ? w1 : 0.f;
      yi[0] = min(max(j0, 0), HH - 1); yi[1] = min(max(j0 + 1, 0), HH - 1);
      float f1 = floorf(q.w); int j1 = (int)f1; float v1 = q.w - f1;
      yw[2] = (j1 >= 0 && j1 < HH) ? -(1.f - v1) : 0.f;
      yw[3] = (j1 + 1 < HH) ? -v1 : 0.f;
      yi[2] = min(max(j1, 0), HH - 1); yi[3] = min(max(j1 + 1, 0), HH - 1);
    }
    const float* base = integ + (size_t)(b * WW) * HH * CC + lane * 4;
    f32x4 val = {0.f, 0.f, 0.f, 0.f};
#pragma unroll
    for (int jj = 0; jj < 4; ++jj) {
      if (yw[jj] == 0.f) continue;          // wave-uniform branch
      const float* rp = base + (size_t)yi[jj] * CC;
      f32x4 rs = {0.f, 0.f, 0.f, 0.f};
#pragma unroll
      for (int ii = 0; ii < 4; ++ii) {
        if (xw[ii] != 0.f) {
          f32x4 v = *(const f32x4*)(rp + (size_t)xi[ii] * HH * CC);
          rs += xw[ii] * v;
        }
      }
      val += yw[jj] * rs;
    }
    val *= scale;
    *dst = bf16x4{(__bf16)val.x, (__bf16)val.y, (__bf16)val.z, (__bf16)val.w};
  }
}

// ---------- async 16B global -> LDS ----------
__device__ __forceinline__ void glds16(const void* g, void* l) {
  __builtin_amdgcn_global_load_lds(
      (const __attribute__((address_space(1))) void*)g,
      (__attribute__((address_space(3))) void*)(uint32_t)(uintptr_t)l,
      16, 0, 0);
}

// ---------- K6: GEMM  C[co, r] = sum_k Wbf[co,k] * vox[r,k]; +bias, relu ----------
// M=256, N=32768, K=1280. 128x128 tiles, bf16 MFMA 16x16x32, 4-buffer LDS
// ring, depth-3 glds prefetch, in-flight-aware vmcnt + raw s_barrier.
// K-loop over the COMPRESSED active K-tile list (8 per visible layer). [R5]
__global__ __launch_bounds__(256) void k6_gemm(const __bf16* __restrict__ A,   // 256 x 1280
                                               const __bf16* __restrict__ Bm,  // 32768 x 1280
                                               const float* __restrict__ bias,
                                               float* __restrict__ out,
                                               const uint8_t* __restrict__ mask8) {
  __shared__ __align__(16) __bf16 As[4][128 * 32];
  __shared__ __align__(16) __bf16 Bs[4][128 * 32];
  __shared__ uint8_t ktsS[NKT];
  __shared__ int LsS;
  const int tileM = blockIdx.y * 128;
  const int tileN = blockIdx.x * 128;
  const int tid = threadIdx.x;
  const int lane = tid & 63;
  const int wave = tid >> 6;
  const int wm = (wave >> 1) * 64;
  const int wn = (wave & 1) * 64;

  if (tid == 0) {
    const uint8_t* mg = mask8 + blockIdx.x * 5;   // N-tile group == blockIdx.x
    int L = 0;
#pragma unroll
    for (int n = 0; n < NLAY; ++n)
      if (mg[n]) {
#pragma unroll
        for (int kk = 0; kk < 8; ++kk) ktsS[L++] = (uint8_t)(n * 8 + kk);
      }
    LsS = L;
  }

  f32x4 acc[4][4];
#pragma unroll
  for (int i = 0; i < 4; ++i)
#pragma unroll
    for (int j = 0; j < 4; ++j)
      acc[i][j] = f32x4{0.f, 0.f, 0.f, 0.f};

  const int r16 = lane & 15;
  const int q4 = lane >> 4;        // 0..3 -> k-chunk
  const int srow = (lane >> 2);
  const int sch = lane & 3;

  auto stage = [&](int buf, int kt) {
    const int k0 = kt * 32;
#pragma unroll
    for (int rr = 0; rr < 2; ++rr) {
      const int base_row = wave * 16 + rr * 64;
      const int row = base_row + srow;
      const int gch = sch ^ ((row >> 1) & 3);
      glds16(A  + (size_t)(tileM + row) * KDIM + k0 + gch * 8,
             (void*)(&As[buf][base_row * 32] + lane * 8));
      glds16(Bm + (size_t)(tileN + row) * KDIM + k0 + gch * 8,
             (void*)(&Bs[buf][base_row * 32] + lane * 8));
    }
  };

  __syncthreads();                       // ktsS/LsS visible
  const int L = LsS;
#pragma unroll
  for (int s = 0; s < 3; ++s)
    if (s < L) stage(s, ktsS[s]);
  for (int i = 0; i < L; ++i) {
    const int cur = i & 3;
    const int rem = L - i;               // stages in flight = min(rem, 3)
    if (rem >= 3)      __builtin_amdgcn_s_waitcnt(0xF78);  // vmcnt(8)
    else if (rem == 2) __builtin_amdgcn_s_waitcnt(0xF74);  // vmcnt(4)
    else               __builtin_amdgcn_s_waitcnt(0xF70);  // vmcnt(0)
    __builtin_amdgcn_s_barrier();
    if (i + 3 < L) stage((i + 3) & 3, ktsS[i + 3]);   // async prefetch, depth 3
    bf16x8 af[4], bg[4];
#pragma unroll
    for (int ii = 0; ii < 4; ++ii) {
      int m = wm + ii * 16 + r16;
      af[ii] = *(const bf16x8*)(&As[cur][m * 32] + (q4 ^ ((m >> 1) & 3)) * 8);
    }
#pragma unroll
    for (int j = 0; j < 4; ++j) {
      int nr = wn + j * 16 + r16;
      bg[j] = *(const bf16x8*)(&Bs[cur][nr * 32] + (q4 ^ ((nr >> 1) & 3)) * 8);
    }
#pragma unroll
    for (int ii = 0; ii < 4; ++ii)
#pragma unroll
      for (int j = 0; j < 4; ++j)
        acc[ii][j] = __builtin_amdgcn_mfma_f32_16x16x32_bf16(af[ii], bg[j], acc[ii][j], 0, 0, 0);
  }

#pragma unroll
  for (int i = 0; i < 4; ++i) {
#pragma unroll
    for (int j = 0; j < 4; ++j) {
      int nn = tileN + wn + j * 16 + r16;
      int bI = nn >> 14;
      int pix = nn & (NPIX - 1);
#pragma unroll
      for (int r = 0; r < 4; ++r) {
        int co = tileM + wm + i * 16 + q4 * 4 + r;
        float v = acc[i][j][r] + bias[co];
        out[(size_t)(bI * CC + co) * NPIX + pix] = fmaxf(v, 0.f);
      }
    }
  }
}

extern "C" void kernel_launch(void* const* d_in, const int* in_sizes, int n_in,
                              void* d_out, int out_size, void* d_ws, size_t ws_size,
                              hipStream_t stream) {
  const float* feat  = (const float*)d_in[0];
  const float* calib = (const float*)d_in[1];
  const float* grid  = (const float*)d_in[2];
  const float* Wc    = (const float*)d_in[3];
  const float* bc    = (const float*)d_in[4];
  float* out = (float*)d_out;

  char* ws = (char*)d_ws;
  const size_t SZ_INTEG = (size_t)BB * HH * WW * CC * 4;   // 62,914,560
  const size_t SZ_VOX   = (size_t)NDIM * KDIM * 2;         // 83,886,080
  const size_t SZ_WBF   = (size_t)CC * KDIM * 2;           //    655,360
  const size_t SZ_CRD   = (size_t)BB * NLAY * NPIX * 16;   //  2,621,440
  const size_t SZ_SCL   = (size_t)BB * NLAY * NPIX * 4;    //    655,360
  const size_t SZ_MSK   = (size_t)NGRP * NLAY;             //      1,280
  if (ws_size < SZ_INTEG + SZ_VOX + SZ_WBF + SZ_CRD + SZ_SCL + SZ_MSK) return;

  // Buffer rotation (R11): X = vox region (k1f out / k2 in, dead before k4
  // writes voxA over it); Y = integ slot (k2 out / k4 taps).
  float*   integY = (float*)ws;
  float*   integX = (float*)(ws + SZ_INTEG);
  __bf16*  voxA   = (__bf16*)(ws + SZ_INTEG);
  __bf16*  Wbf    = (__bf16*)(ws + SZ_INTEG + SZ_VOX);
  float4*  coords = (float4*)(ws + SZ_INTEG + SZ_VOX + SZ_WBF);
  float*   scales = (float*)(ws + SZ_INTEG + SZ_VOX + SZ_WBF + SZ_CRD);
  uint8_t* mask8  = (uint8_t*)(ws + SZ_INTEG + SZ_VOX + SZ_WBF + SZ_CRD + SZ_SCL);

  k1f<<<dim3(BB * HH * 8 + 480), dim3(1024), 0, stream>>>(
      feat, integX, grid, calib, Wc, coords, scales, Wbf, mask8);
  k2_scan<<<dim3(BB * WW), dim3(256), 0, stream>>>(integX, integY);
  k4_vox<<<dim3(BB * NLAY * NPIX / 16), dim3(256), 0, stream>>>(integY, coords, scales, voxA, mask8);
  k6_gemm<<<dim3(NDIM / 128, 2), dim3(256), 0, stream>>>(Wbf, voxA, bc, out, mask8);
}

// Round 13
// 155.365 us; speedup vs baseline: 1.0378x; 1.0249x over previous
//
#include <hip/hip_runtime.h>
#include <hip/hip_bf16.h>
#include <stdint.h>

#define BB 2
#define CC 256
#define HH 96
#define WW 320
#define NPIX 16384
#define NLAY 5
#define KDIM 1280   // CC*NLAY
#define NDIM 32768  // BB*NPIX
#define NKT (KDIM / 32)   // 40 K-tiles
#define NGRP 256    // NDIM/128 output row groups (k6 N-tiles)
#define HG 3        // h rows per k12 block
#define NHG (HH / HG)   // 32 h-groups

typedef float f32x4 __attribute__((ext_vector_type(4)));
typedef float f32x2 __attribute__((ext_vector_type(2)));
typedef __bf16 bf16x8 __attribute__((ext_vector_type(8)));
typedef __bf16 bf16x4 __attribute__((ext_vector_type(4)));

// ---------- R13 = R12 with the out_size guard fixed ----------
// R12 never ran: `out_size` is an ELEMENT count (8,388,608 floats), the
// guard compared it against SZ_T in BYTES (20,971,520) and early-returned
// -> all-zero output (absmax 0.1435 = max|ref|). T-scratch needs SZ_T/4 =
// 5,242,880 floats <= out's 8,388,608: fits. Everything else identical.
//
// R12 design: k2's 126MB round-trip eliminated via hierarchical H-scan.
// k12 block owns HG=3 consecutive h rows of a 32-ch group: per row W-scan
// (proven k1f code) + running H-sum in REGISTERS -> stores P = within-group
// partial integral. Group total T goes to the OUT buffer as scratch (k6
// overwrites out fully afterwards -> zero extra workspace). pt_scan does an
// in-place exclusive prefix of T over the 32 groups. k4 taps become
// P[tap] + PT[ygrp] (16 extra L2-resident f32x4 loads). Linear => identical
// math up to f32 regrouping (same class as old k2's 4x24 two-level scan).

// ---------- K12 (+K3+K5 fused as extra blocks) ----------
// blocks [0,480): box geometry + Wc repack + visibility mask (R5).
// blocks [480, 480+512): W-scan + partial H-scan + transpose.
__global__ __launch_bounds__(1024) void k12(const float* __restrict__ feat,
                                            float* __restrict__ P,
                                            const float* __restrict__ gridp,
                                            const float* __restrict__ calib,
                                            const float* __restrict__ Wc,
                                            float4* __restrict__ coords,
                                            float* __restrict__ scales,
                                            __bf16* __restrict__ Wbf,
                                            uint8_t* __restrict__ mask8,
                                            float* __restrict__ T) {
  const int bid = blockIdx.x;
  if (bid < 480) {
    // ---- K3/K5 part ----
    const int vbid = bid * 4 + (threadIdx.x >> 8);
    const int vt = threadIdx.x & 255;
    if (vbid >= 640) {                  // K5: repack Wc (co, c*5+n) -> bf16 (co, n*256+c)
      int o = (vbid - 640) * 256 + vt;
      int co = o / KDIM;
      int kk = o % KDIM;
      int n = kk >> 8;
      int c = kk & 255;
      Wbf[o] = (__bf16)Wc[co * KDIM + c * NLAY + n];
      return;
    }
    // K3: one thread per box.
    int box = vbid * 256 + vt;          // ((b*5+n)<<14) | pix
    int pix = box & (NPIX - 1);
    int bn = box >> 14;
    int n = bn % NLAY;
    int b = bn / NLAY;
    const float* cb = calib + b * 12;
    float c00 = cb[0], c01 = cb[1], c02 = cb[2], c03 = cb[3];
    float c10 = cb[4], c11 = cb[5], c12 = cb[6], c13 = cb[7];
    float c20 = cb[8], c21 = cb[9], c22 = cb[10], c23 = cb[11];
    float gx = gridp[pix * 3 + 0], gy = gridp[pix * 3 + 1], gz = gridp[pix * 3 + 2];
    float zoff = 32.0f * (float)n;
    const float ox[8] = {-12.5f, 12.5f, 12.5f, -12.5f, -12.5f, 12.5f, 12.5f, -12.5f};
    const float oy[8] = {-12.5f, -12.5f, 12.5f, 12.5f, -12.5f, -12.5f, 12.5f, 12.5f};
    float xmn = 1e30f, ymn = 1e30f, xmx = -1e30f, ymx = -1e30f;
#pragma unroll
    for (int k = 0; k < 8; ++k) {
      float X = gx + ox[k];
      float Y = gy + oy[k];
      float Z = gz + zoff + ((k >= 4) ? 32.0f : 0.0f);
      float px = c00 * X + c01 * Y + c02 * Z + c03;
      float py = c10 * X + c11 * Y + c12 * Z + c13;
      float pz = c20 * X + c21 * Y + c22 * Z + c23;
      float d = fmaxf(pz, 1e-6f);
      float nx = fminf(fmaxf(2.0f * (px / d) / 320.0f - 1.0f, -1.0f), 0.95f);
      float ny = fminf(fmaxf(2.0f * (py / d) / 96.0f - 1.0f, -1.0f), 0.95f);
      xmn = fminf(xmn, nx); xmx = fmaxf(xmx, nx);
      ymn = fminf(ymn, ny); ymx = fmaxf(ymx, ny);
    }
    float dx = xmx - xmn, dy = ymx - ymn;
    float area = (dx * dy) * 30720.0f + 1e-6f;
    bool vis = (area > 1e-6f) && (area < 9216.0f);
    {
      __shared__ uint32_t kf[16];
      unsigned long long bal = __ballot(vis);
      if ((threadIdx.x & 63) == 0) kf[threadIdx.x >> 6] = (bal != 0ull) ? 1u : 0u;
      __syncthreads();
      if (vt == 0) {
        int vb = threadIdx.x >> 8;      // vbid-local 0..3
        int vbid2 = bid * 4 + vb;
        int bn2 = vbid2 >> 6;
        int n2 = bn2 % NLAY, b2 = bn2 / NLAY;
        int g0 = b2 * 128 + (vbid2 & 63) * 2;
        mask8[g0 * 5 + n2]       = (uint8_t)(kf[vb * 4 + 0] | kf[vb * 4 + 1]);
        mask8[(g0 + 1) * 5 + n2] = (uint8_t)(kf[vb * 4 + 2] | kf[vb * 4 + 3]);
      }
    }
    float X0 = ((xmn + 1.0f) * 320.0f - 1.0f) * 0.5f;
    float Y0 = ((ymn + 1.0f) * 96.0f - 1.0f) * 0.5f;
    float X1 = ((xmx + 1.0f) * 320.0f - 1.0f) * 0.5f;
    float Y1 = ((ymx + 1.0f) * 96.0f - 1.0f) * 0.5f;
    coords[box] = make_float4(X0, Y0, X1, Y1);
    scales[box] = vis ? 1.0f / area : 0.0f;
    return;
  }
  // ---- K12 part: 32 channels, HG=3 h-rows; running H-sum in registers ----
  __shared__ float tile[WW * 33];       // 42.2 KB -> 2 blocks/CU (thread-cap)
  const int t = threadIdx.x;
  const int wave = t >> 6;
  const int lane = t & 63;
  const int kb = bid - 480;             // 0..511
  const int cg = kb & 7;
  const int hg = (kb >> 3) & 31;
  const int b = kb >> 8;
  const int h0 = hg * HG;
  const int c0 = cg * 32 + wave * 2;
  const float* s0 = feat + (size_t)((b * CC + c0) * HH) * WW;
  const float* s1 = s0 + (size_t)HH * WW;
  const int ca = wave * 2, cbn = wave * 2 + 1;

  float ra[5] = {0.f, 0.f, 0.f, 0.f, 0.f};
  float rb[5] = {0.f, 0.f, 0.f, 0.f, 0.f};
#pragma unroll
  for (int hh = 0; hh < HG; ++hh) {
    const int h = h0 + hh;
    float va[5], vb[5];
#pragma unroll
    for (int j = 0; j < 5; ++j) va[j] = s0[(size_t)h * WW + lane * 5 + j];
#pragma unroll
    for (int j = 0; j < 5; ++j) vb[j] = s1[(size_t)h * WW + lane * 5 + j];
#pragma unroll
    for (int j = 1; j < 5; ++j) { va[j] += va[j - 1]; vb[j] += vb[j - 1]; }
    float ta = va[4], tb = vb[4];
    float ia = ta, ib = tb;
#pragma unroll
    for (int d = 1; d < 64; d <<= 1) {
      float ua = __shfl_up(ia, d, 64);
      float ub = __shfl_up(ib, d, 64);
      if (lane >= d) { ia += ua; ib += ub; }
    }
    float pa = ia - ta, pb = ib - tb;   // exclusive prefixes
#pragma unroll
    for (int j = 0; j < 5; ++j) {
      va[j] += pa; vb[j] += pb;
      ra[j] += va[j]; rb[j] += vb[j];   // running H-sum (within group)
    }
#pragma unroll
    for (int j = 0; j < 5; ++j) {
      int w = lane * 5 + j;
      tile[w * 33 + ca]  = ra[j];
      tile[w * 33 + cbn] = rb[j];
    }
    __syncthreads();
    // P store: (B,W,H,C) — 8 x 128B full-line single-owner segs per instr
    float* dst = P + ((size_t)(b * WW) * HH + h) * CC + cg * 32;
#pragma unroll
    for (int r = 0; r < 3; ++r) {
      int idx = r * 1024 + t;           // 0..2559
      if (idx < 2560) {
        int w = idx >> 3;
        int cq = (idx & 7) * 4;
        float4 o = make_float4(tile[w * 33 + cq + 0], tile[w * 33 + cq + 1],
                               tile[w * 33 + cq + 2], tile[w * 33 + cq + 3]);
        *(float4*)(dst + (size_t)w * HH * CC + cq) = o;
      }
    }
    if (hh == HG - 1) {
      // T store: tile currently holds the group total. T[b][hg][w][c] — fully
      // contiguous 1KB per wave-instr.
      float* td = T + ((size_t)(b * NHG + hg) * WW) * CC + cg * 32;
#pragma unroll
      for (int r = 0; r < 3; ++r) {
        int idx = r * 1024 + t;
        if (idx < 2560) {
          int w = idx >> 3;
          int cq = (idx & 7) * 4;
          float4 o = make_float4(tile[w * 33 + cq + 0], tile[w * 33 + cq + 1],
                                 tile[w * 33 + cq + 2], tile[w * 33 + cq + 3]);
          *(float4*)(td + (size_t)w * CC + cq) = o;
        }
      }
    }
    __syncthreads();                    // tile reused next row
  }
}

// ---------- PT: in-place exclusive prefix of T over the 32 h-groups ----------
// Thread owns (b,w,c): 32 loads at 327KB stride (1KB coalesced per g),
// in-register exclusive scan, 32 stores. 42MB total ~ 8us.
__global__ __launch_bounds__(256) void pt_scan(float* __restrict__ T) {
  const int w = blockIdx.x % WW;
  const int b = blockIdx.x / WW;
  const int c = threadIdx.x;
  float* p = T + ((size_t)(b * NHG) * WW + w) * CC + c;
  const size_t gs = (size_t)WW * CC;
  float v[NHG];
#pragma unroll
  for (int g = 0; g < NHG; ++g) v[g] = p[(size_t)g * gs];
  float run = 0.f;
#pragma unroll
  for (int g = 0; g < NHG; ++g) { float x = v[g]; p[(size_t)g * gs] = run; run += x; }
}

// ---------- K4: box-filtered features -> vox (bf16) ----------
// Tap = P[xi,yi] + PT[ygrp(yi), xi]  (integral = partial + group prefix).
// FOUR boxes per wave, mask early-out (R5). (B,W,H,C) P layout.
__global__ __launch_bounds__(256) void k4_vox(const float* __restrict__ P,
                                              const float4* __restrict__ coords,
                                              const float* __restrict__ scales,
                                              __bf16* __restrict__ voxA,
                                              const uint8_t* __restrict__ mask8,
                                              const float* __restrict__ PT) {
  const int wave = threadIdx.x >> 6;
  const int lane = threadIdx.x & 63;
  const int box0 = (blockIdx.x * 4 + wave) * 4;
  {
    const int pix0 = box0 & (NPIX - 1);
    const int bn0 = box0 >> 14;
    const int n0 = bn0 % NLAY, b0 = bn0 / NLAY;
    if (mask8[((b0 * NPIX + pix0) >> 7) * 5 + n0] == 0) return;  // wave-uniform
  }
#pragma unroll
  for (int u = 0; u < 4; ++u) {
    const int box = box0 + u;
    const int pix = box & (NPIX - 1);
    const int bn = box >> 14;
    const int n = bn % NLAY;
    const int b = bn / NLAY;
    const size_t row = (size_t)(b * NPIX + pix);
    bf16x4* dst = (bf16x4*)(voxA + row * KDIM + n * CC + lane * 4);
    const float scale = scales[box];
    if (scale == 0.f) {                 // wave-uniform branch
      *dst = bf16x4{(__bf16)0.f, (__bf16)0.f, (__bf16)0.f, (__bf16)0.f};
      continue;
    }
    const float4 q = coords[box];

    float xw[4]; int xi[4];
    float yw[4]; int yi[4];
    {
      float f0 = floorf(q.x); int i0 = (int)f0; float w1 = q.x - f0;
      xw[0] = (i0 >= 0 && i0 < WW) ? (1.f - w1) : 0.f;
      xw[1] = (i0 + 1 < WW) ? w1 : 0.f;
      xi[0] = min(max(i0, 0), WW - 1); xi[1] = min(max(i0 + 1, 0), WW - 1);
      float f1 = floorf(q.z); int i1 = (int)f1; float v1 = q.z - f1;
      xw[2] = (i1 >= 0 && i1 < WW) ? -(1.f - v1) : 0.f;
      xw[3] = (i1 + 1 < WW) ? -v1 : 0.f;
      xi[2] = min(max(i1, 0), WW - 1); xi[3] = min(max(i1 + 1, 0), WW - 1);
    }
    {
      float f0 = floorf(q.y); int j0 = (int)f0; float w1 = q.y - f0;
      yw[0] = (j0 >= 0 && j0 < HH) ? (1.f - w1) : 0.f;
      yw[1] = (j0 + 1 < HH) ? w1 : 0.f;
      yi[0] = min(max(j0, 0), HH - 1); yi[1] = min(max(j0 + 1, 0), HH - 1);
      float f1 = floorf(q.w); int j1 = (int)f1; float v1 = q.w - f1;
      yw[2] = (j1 >= 0 && j1 < HH) ? -(1.f - v1) : 0.f;
      yw[3] = (j1 + 1 < HH) ? -v1 : 0.f;
      yi[2] = min(max(j1, 0), HH - 1); yi[3] = min(max(j1 + 1, 0), HH - 1);
    }
    const float* base = P + (size_t)(b * WW) * HH * CC + lane * 4;
    const float* ptb = PT + (size_t)(b * NHG) * WW * CC + lane * 4;
    f32x4 val = {0.f, 0.f, 0.f, 0.f};
#pragma unroll
    for (int jj = 0; jj < 4; ++jj) {
      if (yw[jj] == 0.f) continue;          // wave-uniform branch
      const int yg = yi[jj] / HG;
      const float* rp = base + (size_t)yi[jj] * CC;
      const float* pp = ptb + (size_t)yg * WW * CC;
      f32x4 rs = {0.f, 0.f, 0.f, 0.f};
#pragma unroll
      for (int ii = 0; ii < 4; ++ii) {
        if (xw[ii] != 0.f) {
          f32x4 v = *(const f32x4*)(rp + (size_t)xi[ii] * HH * CC)
                  + *(const f32x4*)(pp + (size_t)xi[ii] * CC);
          rs += xw[ii] * v;
        }
      }
      val += yw[jj] * rs;
    }
    val *= scale;
    *dst = bf16x4{(__bf16)val.x, (__bf16)val.y, (__bf16)val.z, (__bf16)val.w};
  }
}

// ---------- async 16B global -> LDS ----------
__device__ __forceinline__ void glds16(const void* g, void* l) {
  __builtin_amdgcn_global_load_lds(
      (const __attribute__((address_space(1))) void*)g,
      (__attribute__((address_space(3))) void*)(uint32_t)(uintptr_t)l,
      16, 0, 0);
}

// ---------- K6: GEMM  C[co, r] = sum_k Wbf[co,k] * vox[r,k]; +bias, relu ----------
// M=256, N=32768, K=1280. 128x128 tiles, bf16 MFMA 16x16x32, 4-buffer LDS
// ring, depth-3 glds prefetch, in-flight-aware vmcnt + raw s_barrier.
// K-loop over the COMPRESSED active K-tile list (8 per visible layer). [R5]
__global__ __launch_bounds__(256) void k6_gemm(const __bf16* __restrict__ A,   // 256 x 1280
                                               const __bf16* __restrict__ Bm,  // 32768 x 1280
                                               const float* __restrict__ bias,
                                               float* __restrict__ out,
                                               const uint8_t* __restrict__ mask8) {
  __shared__ __align__(16) __bf16 As[4][128 * 32];
  __shared__ __align__(16) __bf16 Bs[4][128 * 32];
  __shared__ uint8_t ktsS[NKT];
  __shared__ int LsS;
  const int tileM = blockIdx.y * 128;
  const int tileN = blockIdx.x * 128;
  const int tid = threadIdx.x;
  const int lane = tid & 63;
  const int wave = tid >> 6;
  const int wm = (wave >> 1) * 64;
  const int wn = (wave & 1) * 64;

  if (tid == 0) {
    const uint8_t* mg = mask8 + blockIdx.x * 5;   // N-tile group == blockIdx.x
    int L = 0;
#pragma unroll
    for (int n = 0; n < NLAY; ++n)
      if (mg[n]) {
#pragma unroll
        for (int kk = 0; kk < 8; ++kk) ktsS[L++] = (uint8_t)(n * 8 + kk);
      }
    LsS = L;
  }

  f32x4 acc[4][4];
#pragma unroll
  for (int i = 0; i < 4; ++i)
#pragma unroll
    for (int j = 0; j < 4; ++j)
      acc[i][j] = f32x4{0.f, 0.f, 0.f, 0.f};

  const int r16 = lane & 15;
  const int q4 = lane >> 4;        // 0..3 -> k-chunk
  const int srow = (lane >> 2);
  const int sch = lane & 3;

  auto stage = [&](int buf, int kt) {
    const int k0 = kt * 32;
#pragma unroll
    for (int rr = 0; rr < 2; ++rr) {
      const int base_row = wave * 16 + rr * 64;
      const int row = base_row + srow;
      const int gch = sch ^ ((row >> 1) & 3);
      glds16(A  + (size_t)(tileM + row) * KDIM + k0 + gch * 8,
             (void*)(&As[buf][base_row * 32] + lane * 8));
      glds16(Bm + (size_t)(tileN + row) * KDIM + k0 + gch * 8,
             (void*)(&Bs[buf][base_row * 32] + lane * 8));
    }
  };

  __syncthreads();                       // ktsS/LsS visible
  const int L = LsS;
#pragma unroll
  for (int s = 0; s < 3; ++s)
    if (s < L) stage(s, ktsS[s]);
  for (int i = 0; i < L; ++i) {
    const int cur = i & 3;
    const int rem = L - i;               // stages in flight = min(rem, 3)
    if (rem >= 3)      __builtin_amdgcn_s_waitcnt(0xF78);  // vmcnt(8)
    else if (rem == 2) __builtin_amdgcn_s_waitcnt(0xF74);  // vmcnt(4)
    else               __builtin_amdgcn_s_waitcnt(0xF70);  // vmcnt(0)
    __builtin_amdgcn_s_barrier();
    if (i + 3 < L) stage((i + 3) & 3, ktsS[i + 3]);   // async prefetch, depth 3
    bf16x8 af[4], bg[4];
#pragma unroll
    for (int ii = 0; ii < 4; ++ii) {
      int m = wm + ii * 16 + r16;
      af[ii] = *(const bf16x8*)(&As[cur][m * 32] + (q4 ^ ((m >> 1) & 3)) * 8);
    }
#pragma unroll
    for (int j = 0; j < 4; ++j) {
      int nr = wn + j * 16 + r16;
      bg[j] = *(const bf16x8*)(&Bs[cur][nr * 32] + (q4 ^ ((nr >> 1) & 3)) * 8);
    }
#pragma unroll
    for (int ii = 0; ii < 4; ++ii)
#pragma unroll
      for (int j = 0; j < 4; ++j)
        acc[ii][j] = __builtin_amdgcn_mfma_f32_16x16x32_bf16(af[ii], bg[j], acc[ii][j], 0, 0, 0);
  }

#pragma unroll
  for (int i = 0; i < 4; ++i) {
#pragma unroll
    for (int j = 0; j < 4; ++j) {
      int nn = tileN + wn + j * 16 + r16;
      int bI = nn >> 14;
      int pix = nn & (NPIX - 1);
#pragma unroll
      for (int r = 0; r < 4; ++r) {
        int co = tileM + wm + i * 16 + q4 * 4 + r;
        float v = acc[i][j][r] + bias[co];
        out[(size_t)(bI * CC + co) * NPIX + pix] = fmaxf(v, 0.f);
      }
    }
  }
}

extern "C" void kernel_launch(void* const* d_in, const int* in_sizes, int n_in,
                              void* d_out, int out_size, void* d_ws, size_t ws_size,
                              hipStream_t stream) {
  const float* feat  = (const float*)d_in[0];
  const float* calib = (const float*)d_in[1];
  const float* grid  = (const float*)d_in[2];
  const float* Wc    = (const float*)d_in[3];
  const float* bc    = (const float*)d_in[4];
  float* out = (float*)d_out;

  char* ws = (char*)d_ws;
  const size_t SZ_INTEG = (size_t)BB * HH * WW * CC * 4;   // 62,914,560
  const size_t SZ_VOX   = (size_t)NDIM * KDIM * 2;         // 83,886,080
  const size_t SZ_WBF   = (size_t)CC * KDIM * 2;           //    655,360
  const size_t SZ_CRD   = (size_t)BB * NLAY * NPIX * 16;   //  2,621,440
  const size_t SZ_SCL   = (size_t)BB * NLAY * NPIX * 4;    //    655,360
  const size_t SZ_MSK   = (size_t)NGRP * NLAY;             //      1,280
  const size_t NT_ELEM  = (size_t)BB * NHG * WW * CC;      //  5,242,880 floats
  if (ws_size < SZ_INTEG + SZ_VOX + SZ_WBF + SZ_CRD + SZ_SCL + SZ_MSK) return;
  if ((size_t)out_size < NT_ELEM) return;  // out (8,388,608 elems) >= T-scratch

  float*   integ  = (float*)ws;                            // P (partial integral)
  __bf16*  voxA   = (__bf16*)(ws + SZ_INTEG);
  __bf16*  Wbf    = (__bf16*)(ws + SZ_INTEG + SZ_VOX);
  float4*  coords = (float4*)(ws + SZ_INTEG + SZ_VOX + SZ_WBF);
  float*   scales = (float*)(ws + SZ_INTEG + SZ_VOX + SZ_WBF + SZ_CRD);
  uint8_t* mask8  = (uint8_t*)(ws + SZ_INTEG + SZ_VOX + SZ_WBF + SZ_CRD + SZ_SCL);
  float*   Tscr   = out;                 // T/PT scratch; k6 overwrites out fully

  k12<<<dim3(480 + BB * NHG * 8), dim3(1024), 0, stream>>>(
      feat, integ, grid, calib, Wc, coords, scales, Wbf, mask8, Tscr);
  pt_scan<<<dim3(BB * WW), dim3(256), 0, stream>>>(Tscr);
  k4_vox<<<dim3(BB * NLAY * NPIX / 16), dim3(256), 0, stream>>>(
      integ, coords, scales, voxA, mask8, Tscr);
  k6_gemm<<<dim3(NDIM / 128, 2), dim3(256), 0, stream>>>(Wbf, voxA, bc, out, mask8);
}